// Round 6
// baseline (350.340 us; speedup 1.0000x reference)
//
#include <hip/hip_runtime.h>
#include <math.h>

#define NB 96
#define NB2 (NB * NB)
#define DFEAT 64
#define NCLS 21
#define MARGIN 0.3

typedef int i4 __attribute__((ext_vector_type(4)));
typedef unsigned int u32;

// ---------------------------------------------------------------------------
// Fused kernel A: one block per anchor i (96 blocks x 128 threads).
// Phase 1: stage logits_i / labels_i in LDS; thread j computes (all f64 so
//          boolean compares vs the float64 numpy reference are exact):
//            mat[i,j]   = -cos_sim(logits_i, feat2_j)
//            share[i,j] = (labels_i . labels_j) > 0
// Phase 2: same block builds the 96-bit row masks:
//            rowmask[i][p][n] = !share[i,n] && (mat[i,n] <= MARGIN + mat[i,p])
// ---------------------------------------------------------------------------
__global__ __launch_bounds__(128) void fused_pre_kernel(const float* __restrict__ logits,
                                                        const float* __restrict__ labels,
                                                        const float* __restrict__ feat2,
                                                        double* __restrict__ mat,
                                                        unsigned char* __restrict__ share,
                                                        u32* __restrict__ mask4) {
    const int i = blockIdx.x;
    const int tid = threadIdx.x;

    __shared__ float sx[DFEAT];        // logits_i
    __shared__ float sl[NCLS];         // labels_i
    __shared__ double sm[NB];          // mat row i
    __shared__ unsigned char ss[NB];   // share row i
    __shared__ u32 sdiff[3];           // diffs bits

    if (tid < DFEAT) sx[tid] = logits[i * DFEAT + tid];
    if (tid < NCLS) sl[tid] = labels[i * NCLS + tid];
    __syncthreads();

    if (tid < NB) {
        const int j = tid;
        const float* yj = feat2 + j * DFEAT;
        double nx = 0.0, ny = 0.0, dot = 0.0;
#pragma unroll
        for (int d = 0; d < DFEAT; ++d) {
            double a = (double)sx[d];
            double b = (double)yj[d];
            nx += a * a;
            ny += b * b;
            dot += a * b;
        }
        nx = fmax(sqrt(nx), 1e-12);
        ny = fmax(sqrt(ny), 1e-12);
        double m = -(dot / (nx * ny));
        sm[j] = m;
        mat[i * NB + j] = m;

        const float* lj = labels + j * NCLS;
        float ldot = 0.f;
#pragma unroll
        for (int c = 0; c < NCLS; ++c) ldot += sl[c] * lj[c];
        unsigned char s = (ldot > 0.f) ? 1 : 0;
        ss[j] = s;
        share[i * NB + j] = s;
    }
    __syncthreads();

    if (tid < 3) {
        u32 w = 0;
        const unsigned char* srow = ss + tid * 32;
#pragma unroll
        for (int n = 0; n < 32; ++n)
            if (!srow[n]) w |= (1u << n);
        sdiff[tid] = w;
    }
    __syncthreads();

    if (tid < NB) {
        const int p = tid;
        const double t = MARGIN + sm[p];
        u32 w0 = 0, w1 = 0, w2 = 0;
#pragma unroll
        for (int n = 0; n < 32; ++n) if (sm[n] <= t)      w0 |= (1u << n);
#pragma unroll
        for (int n = 0; n < 32; ++n) if (sm[32 + n] <= t) w1 |= (1u << n);
#pragma unroll
        for (int n = 0; n < 32; ++n) if (sm[64 + n] <= t) w2 |= (1u << n);
        const int gid = i * NB + p;
        mask4[gid * 4 + 0] = w0 & sdiff[0];
        mask4[gid * 4 + 1] = w1 & sdiff[1];
        mask4[gid * 4 + 2] = w2 & sdiff[2];
        mask4[gid * 4 + 3] = 0;
    }
}

// ---------------------------------------------------------------------------
// Kernel B: one block per (i,j); writes the 96x96 (k,n) int32 0/1 slab.
// Per k the row is zero or rowmask[i][argmax(mat[i,j],mat[i,k])].
// Inner loop: LDS word read + bit extract + coalesced dwordx4 store.
// ---------------------------------------------------------------------------
__global__ __launch_bounds__(256) void quad_kernel(const double* __restrict__ mat,
                                                   const unsigned char* __restrict__ share,
                                                   const u32* __restrict__ mask4,
                                                   int* __restrict__ out) {
    const int bid = blockIdx.x;
    const int i = bid / NB;
    const int j = bid - i * NB;
    const int tid = threadIdx.x;

    __shared__ u32 vrow[NB][4];  // per-k row mask (already validity-masked)

    if (tid < NB) {
        const int k = tid;
        const double mat_j = mat[i * NB + j];
        const bool sames_ij = share[i * NB + j] && (j != i);
        const bool ok = sames_ij && share[i * NB + k] && (k != i) && (j < k);
        u32 r0 = 0, r1 = 0, r2 = 0;
        if (ok) {
            int p = (mat[i * NB + k] > mat_j) ? k : j;  // argmax mat[i,p]
            const u32* mp = mask4 + (size_t)(i * NB + p) * 4;
            r0 = mp[0]; r1 = mp[1]; r2 = mp[2];
        }
        vrow[k][0] = r0; vrow[k][1] = r1; vrow[k][2] = r2; vrow[k][3] = 0;
    }
    __syncthreads();

    i4* outp = (i4*)(out + (size_t)bid * (size_t)NB2);

    // 96 k-rows * 24 int4-chunks per row = 2304 chunks; 256 threads -> 9 each.
#pragma unroll
    for (int r = 0; r < 9; ++r) {
        int c = r * 256 + tid;
        int k = c / 24;
        int q = c - k * 24;          // chunk within row: covers n = 4q..4q+3
        u32 w = vrow[k][q >> 3];
        u32 b = w >> ((q & 7) * 4);
        i4 v;
        v.x = (int)(b & 1u);
        v.y = (int)((b >> 1) & 1u);
        v.z = (int)((b >> 2) & 1u);
        v.w = (int)((b >> 3) & 1u);
        outp[c] = v;
    }
}

extern "C" void kernel_launch(void* const* d_in, const int* in_sizes, int n_in,
                              void* d_out, int out_size, void* d_ws, size_t ws_size,
                              hipStream_t stream) {
    const float* logits = (const float*)d_in[0]; // [96,64]
    const float* labels = (const float*)d_in[1]; // [96,21]
    const float* feat2  = (const float*)d_in[2]; // [96,64]
    int* out = (int*)d_out;                      // [96,96,96,96] as 0/1 int32

    double* mat = (double*)d_ws;                        // 9216 doubles (73.7 KB)
    unsigned char* share = (unsigned char*)(mat + NB2); // 9216 bytes
    size_t off = (size_t)(share + NB2 - (unsigned char*)d_ws);
    off = (off + 15) & ~(size_t)15;
    u32* mask4 = (u32*)((unsigned char*)d_ws + off);    // 9216*4 u32 (147 KB)

    fused_pre_kernel<<<NB, 128, 0, stream>>>(logits, labels, feat2, mat, share, mask4);
    quad_kernel<<<NB2, 256, 0, stream>>>(mat, share, mask4, out);
}

// Round 7
// 347.003 us; speedup vs baseline: 1.0096x; 1.0096x over previous
//
#include <hip/hip_runtime.h>
#include <math.h>

#define NB 96
#define NB2 (NB * NB)
#define DFEAT 64
#define NCLS 21
#define MARGIN 0.3
#define NCHUNK (NB2 * NB2 / 4)      // 21,233,664 16-B output chunks
#define K2_BLOCKS 10368             // NCHUNK / (256*8) exactly
#define K2_PER_THREAD 8

typedef int i4 __attribute__((ext_vector_type(4)));
typedef unsigned int u32;

// ---------------------------------------------------------------------------
// K1: one block per anchor i. Computes everything except the final stream:
//   phase A: mat row (f64, exact vs float64 numpy ref) + share row
//   phase B: diffs bits; rowmask[p] = diffs & (mat <= MARGIN + mat[p])
//   phase C: vrowg[(i*96+j)*96+k] = valid(i,j,k) ? rowmask[argmax(mat_j,mat_k)] : 0
// vrowg: 884,736 rows x 16 B = 14.2 MB in workspace, coalesced dwordx4 writes.
// ---------------------------------------------------------------------------
__global__ __launch_bounds__(256) void pre_kernel(const float* __restrict__ logits,
                                                  const float* __restrict__ labels,
                                                  const float* __restrict__ feat2,
                                                  i4* __restrict__ vrowg) {
    const int i = blockIdx.x;
    const int tid = threadIdx.x;

    __shared__ float sx[DFEAT];        // logits_i
    __shared__ float sl[NCLS];         // labels_i
    __shared__ double sm[NB];          // mat row i
    __shared__ unsigned char ss[NB];   // share row i
    __shared__ u32 sdiff[3];           // !share bits
    __shared__ u32 smask[NB][4];       // rowmask per p (word 3 = 0)

    if (tid < DFEAT) sx[tid] = logits[i * DFEAT + tid];
    if (tid < NCLS) sl[tid] = labels[i * NCLS + tid];
    __syncthreads();

    if (tid < NB) {
        const int j = tid;
        const float* yj = feat2 + j * DFEAT;
        double nx = 0.0, ny = 0.0, dot = 0.0;
#pragma unroll
        for (int d = 0; d < DFEAT; ++d) {
            double a = (double)sx[d];
            double b = (double)yj[d];
            nx += a * a;
            ny += b * b;
            dot += a * b;
        }
        nx = fmax(sqrt(nx), 1e-12);
        ny = fmax(sqrt(ny), 1e-12);
        sm[j] = -(dot / (nx * ny));

        const float* lj = labels + j * NCLS;
        float ldot = 0.f;
#pragma unroll
        for (int c = 0; c < NCLS; ++c) ldot += sl[c] * lj[c];
        ss[j] = (ldot > 0.f) ? 1 : 0;
    }
    __syncthreads();

    if (tid < 3) {
        u32 w = 0;
        const unsigned char* srow = ss + tid * 32;
#pragma unroll
        for (int n = 0; n < 32; ++n)
            if (!srow[n]) w |= (1u << n);
        sdiff[tid] = w;
    }
    __syncthreads();

    if (tid < NB) {
        const int p = tid;
        const double t = MARGIN + sm[p];
        u32 w0 = 0, w1 = 0, w2 = 0;
#pragma unroll
        for (int n = 0; n < 32; ++n) if (sm[n] <= t)      w0 |= (1u << n);
#pragma unroll
        for (int n = 0; n < 32; ++n) if (sm[32 + n] <= t) w1 |= (1u << n);
#pragma unroll
        for (int n = 0; n < 32; ++n) if (sm[64 + n] <= t) w2 |= (1u << n);
        smask[p][0] = w0 & sdiff[0];
        smask[p][1] = w1 & sdiff[1];
        smask[p][2] = w2 & sdiff[2];
        smask[p][3] = 0;
    }
    __syncthreads();

    // phase C: 9216 (j,k) pairs, 36 iterations of 256 threads; consecutive
    // threads -> consecutive k -> coalesced 16-B-stride dwordx4 stores.
#pragma unroll
    for (int it = 0; it < 36; ++it) {
        int idx = it * 256 + tid;
        int j = idx / NB;
        int k = idx - j * NB;
        bool ok = ss[j] && ss[k] && (j != i) && (k != i) && (j < k);
        i4 v = (i4)(0);
        if (ok) {
            int p = (sm[k] > sm[j]) ? k : j;   // argmax mat[i,p]
            v.x = (int)smask[p][0];
            v.y = (int)smask[p][1];
            v.z = (int)smask[p][2];
            v.w = 0;
        }
        vrowg[(size_t)(i * NB + j) * NB + k] = v;
    }
}

// ---------------------------------------------------------------------------
// K2: pure streaming store kernel (fill-shaped: no LDS, no barrier, no block
// setup). chunk c covers n = 4q..4q+3 of row = c/24; bits live in word
// vrowg_u32[row*4 + (q>>3)] at nibble (q&7)*4. 14 MB of reads (L2) feeding
// 332 MB of nontemporal dwordx4 stores.
// ---------------------------------------------------------------------------
__global__ __launch_bounds__(256) void stream_kernel(const u32* __restrict__ vrowg,
                                                     int* __restrict__ out) {
    const u32 stride = K2_BLOCKS * 256;
    u32 c = blockIdx.x * 256 + threadIdx.x;
    i4* outp = (i4*)out;
#pragma unroll
    for (int t = 0; t < K2_PER_THREAD; ++t, c += stride) {
        u32 row = c / 24u;
        u32 q = c - row * 24u;
        u32 w = vrowg[(row << 2) + (q >> 3)];
        u32 b = w >> ((q & 7u) * 4u);
        i4 v;
        v.x = (int)(b & 1u);
        v.y = (int)((b >> 1) & 1u);
        v.z = (int)((b >> 2) & 1u);
        v.w = (int)((b >> 3) & 1u);
        __builtin_nontemporal_store(v, &outp[c]);
    }
}

extern "C" void kernel_launch(void* const* d_in, const int* in_sizes, int n_in,
                              void* d_out, int out_size, void* d_ws, size_t ws_size,
                              hipStream_t stream) {
    const float* logits = (const float*)d_in[0]; // [96,64]
    const float* labels = (const float*)d_in[1]; // [96,21]
    const float* feat2  = (const float*)d_in[2]; // [96,64]
    int* out = (int*)d_out;                      // [96,96,96,96] as 0/1 int32

    i4* vrowg = (i4*)d_ws;                       // 884,736 x 16 B = 14.2 MB

    pre_kernel<<<NB, 256, 0, stream>>>(logits, labels, feat2, vrowg);
    stream_kernel<<<K2_BLOCKS, 256, 0, stream>>>((const u32*)d_ws, out);
}